// Round 4
// baseline (28416.122 us; speedup 1.0000x reference)
//
#include <hip/hip_runtime.h>
#include <cstdint>
#include <cstddef>

// GRU_56607668961499: B=128, T=512, PRED=24, F=16, L=8, H=1024
// R10: FUSE role-1 (wih1@h0) + role-2 (whh1@h1 + epilogue) into one block so
// gi never leaves registers. WRITE_SIZE forensics (R6): 2.56 MB dirty/tick =
// h0(0.5) + h1(0.5) + gi(1.5) -- gi was 60% of the per-tick wbl2 drain plus
// 1.5 MB/tick of refetch. The old split existed only because whh1+wih1 =
// 2x96KB > LDS. Unlock: whh1 stays in LDS; wih1 is streamed as the MFMA
// B-operand from a BLOCK-PRIVATE f16 copy in workspace (staged once at init,
// unswizzled, L2/MALL-resident read-only). 208 -> 144 blocks, one pipeline
// stage removed (h1[s-1] now computed at tick s from h0[s-1] + h1[s-2]).
// R9 post-mortem: forced asm ring spilled (VGPR capped at 128, FETCH +47%)
// -> reverted to R7's proven gemm for role-0; fused gemm uses a plain loop.
// Barrier/publish protocol: R6/R7 verbatim (proven).

typedef _Float16 f16;
typedef f16 f16x8 __attribute__((ext_vector_type(8)));
typedef float f32x4 __attribute__((ext_vector_type(4)));

#define NB 144
#define NT 512
#define H_ 1024
#define HSLOT 262144       // f16 per h ring slot ([plane][128][1024])

__device__ __forceinline__ float sigm(float x) { return 1.0f / (1.0f + __expf(-x)); }

// ---------------- init barrier (R4 style, per-block fences — proven) ---------
__device__ __forceinline__ void gbar(int* flags, int* rel, int phase) {
  __syncthreads();
  const int tid = threadIdx.x;
  if (blockIdx.x == 0) {
    if (tid == 0) {
      __builtin_amdgcn_fence(__ATOMIC_RELEASE, "agent");
      __hip_atomic_store(&flags[0], phase, __ATOMIC_RELAXED, __HIP_MEMORY_SCOPE_AGENT);
    }
    if (tid < NB) {
      while (__hip_atomic_load(&flags[tid], __ATOMIC_RELAXED, __HIP_MEMORY_SCOPE_AGENT) < phase)
        __builtin_amdgcn_s_sleep(1);
    }
    __syncthreads();
    if (tid == 0) {
      __hip_atomic_store(rel, phase, __ATOMIC_RELAXED, __HIP_MEMORY_SCOPE_AGENT);
      __builtin_amdgcn_fence(__ATOMIC_ACQUIRE, "agent");
    }
  } else {
    if (tid == 0) {
      __builtin_amdgcn_fence(__ATOMIC_RELEASE, "agent");
      __hip_atomic_store(&flags[blockIdx.x], phase, __ATOMIC_RELAXED, __HIP_MEMORY_SCOPE_AGENT);
      while (__hip_atomic_load(rel, __ATOMIC_RELAXED, __HIP_MEMORY_SCOPE_AGENT) < phase)
        __builtin_amdgcn_s_sleep(1);
      __builtin_amdgcn_fence(__ATOMIC_ACQUIRE, "agent");
    }
  }
  __syncthreads();
}

// ------- fast barrier: leader wbl2 each tick; inv only every 4th (R6) -------
__device__ __forceinline__ void fastbar(int* flags2, int* done, int fph, int nl,
                                        bool lead) {
  __syncthreads();   // drains each wave's vmcnt -> all stores complete in L2
  const int tid = threadIdx.x;
  if (tid == 0)
    __hip_atomic_store(&flags2[blockIdx.x], fph, __ATOMIC_RELAXED, __HIP_MEMORY_SCOPE_AGENT);
  if (lead) {
    if (tid < NB) {
      while (__hip_atomic_load(&flags2[tid], __ATOMIC_RELAXED, __HIP_MEMORY_SCOPE_AGENT) < fph)
        __builtin_amdgcn_s_sleep(1);
    }
    __syncthreads();
    if (tid == 0) {
      // publish this XCD's dirty lines to the coherence point (wbl2)
      __builtin_amdgcn_fence(__ATOMIC_RELEASE, "agent");
      // ring-recycle inv: only every 4th phase (reuse distance >= 7 phases)
      if ((fph & 3) == 0)
        __builtin_amdgcn_fence(__ATOMIC_ACQUIRE, "agent");
      __hip_atomic_fetch_add(done, 1, __ATOMIC_RELAXED, __HIP_MEMORY_SCOPE_AGENT);
    }
  }
  if (tid == 0) {
    const int tgt = fph * nl;
    while (__hip_atomic_load(done, __ATOMIC_RELAXED, __HIP_MEMORY_SCOPE_AGENT) < tgt)
      __builtin_amdgcn_s_sleep(1);
  }
  __syncthreads();
}

// ------------- stage 48 rows x 1024 K of fp32 weights -> fp16 LDS, swizzled --
__device__ __forceinline__ void stage_W48(const float* __restrict__ W, int Ubase,
                                          f16* Wsh, int tid) {
  for (int i = tid; i < 6144; i += NT) {
    int row = i >> 7;      // 0..47  ([gate][unit])
    int k8 = i & 127;
    const float* src = W + ((size_t)((row >> 4) << 10) + Ubase + (row & 15)) * H_ + (k8 << 3);
    float4 a = *(const float4*)(src);
    float4 b = *(const float4*)(src + 4);
    f16x8 v;
    v[0] = (f16)a.x; v[1] = (f16)a.y; v[2] = (f16)a.z; v[3] = (f16)a.w;
    v[4] = (f16)b.x; v[5] = (f16)b.y; v[6] = (f16)b.z; v[7] = (f16)b.w;
    *(f16x8*)(Wsh + ((row << 10) + ((k8 ^ (row & 7)) << 3))) = v;
  }
}

// ------------- stage 48 x 1024 fp32 -> fp16 GLOBAL chunk (unswizzled) --------
__device__ __forceinline__ void stage_W48_global(const float* __restrict__ W, int Ubase,
                                                 f16* wchunk, int tid) {
  for (int i = tid; i < 6144; i += NT) {
    int row = i >> 7;
    int k8 = i & 127;
    const float* src = W + ((size_t)((row >> 4) << 10) + Ubase + (row & 15)) * H_ + (k8 << 3);
    float4 a = *(const float4*)(src);
    float4 b = *(const float4*)(src + 4);
    f16x8 v;
    v[0] = (f16)a.x; v[1] = (f16)a.y; v[2] = (f16)a.z; v[3] = (f16)a.w;
    v[4] = (f16)b.x; v[5] = (f16)b.y; v[6] = (f16)b.z; v[7] = (f16)b.w;
    *(f16x8*)(wchunk + ((row << 10) + (k8 << 3))) = v;
  }
}

__device__ __forceinline__ void stage_wih(const float* __restrict__ W, int Ubase,
                                          f16* wih_s, int tid) {
  for (int i = tid; i < 48 * 32; i += NT) {
    int row = i >> 5, k = i & 31;
    float v = (k < 24) ? W[((size_t)((row >> 4) << 10) + Ubase + (row & 15)) * 24 + k] : 0.f;
    wih_s[row * 32 + k] = (f16)v;
  }
}

// ---------------- K=1024 3-gate GEMM, A = hi+lo fp16 planes (R7, proven) -----
__device__ __forceinline__ void gemmK1024(const f16* __restrict__ Ahp,
                                          const f16* __restrict__ Alp,
                                          const f16* Wsh, int lane, int wv, int rot,
                                          f32x4& aR, f32x4& aZ, f32x4& aN) {
  const int q = lane >> 4, r = lane & 15;
  const f16* pa = Ahp + (size_t)(wv * 16 + r) * H_ + q * 8;
  const f16* pl = Alp + (size_t)(wv * 16 + r) * H_ + q * 8;
  const f16* w0 = Wsh + ((0 * 16 + r) << 10);
  const f16* w1 = Wsh + ((1 * 16 + r) << 10);
  const f16* w2 = Wsh + ((2 * 16 + r) << 10);
  const int sw = r & 7;
  f16x8 bh[4][4], bl[4][4];
#pragma unroll
  for (int g = 0; g < 3; ++g) {
#pragma unroll
    for (int j = 0; j < 4; ++j) {
      int kk = (g * 4 + j + rot) & 31;
      bh[g][j] = *(const f16x8*)(pa + kk * 32);
      bl[g][j] = *(const f16x8*)(pl + kk * 32);
    }
  }
#pragma unroll
  for (int g = 0; g < 8; ++g) {
    if (g < 5) {
      int gg = g + 3;
#pragma unroll
      for (int j = 0; j < 4; ++j) {
        int kk = (gg * 4 + j + rot) & 31;
        bh[gg & 3][j] = *(const f16x8*)(pa + kk * 32);
        bl[gg & 3][j] = *(const f16x8*)(pl + kk * 32);
      }
    }
#pragma unroll
    for (int j = 0; j < 4; ++j) {
      int kk = (g * 4 + j + rot) & 31;
      int ko = ((kk * 4 + q) ^ sw) << 3;
      f16x8 B0 = *(const f16x8*)(w0 + ko);
      f16x8 B1 = *(const f16x8*)(w1 + ko);
      f16x8 B2 = *(const f16x8*)(w2 + ko);
      f16x8 Ah = bh[g & 3][j], Al = bl[g & 3][j];
      aR = __builtin_amdgcn_mfma_f32_16x16x32_f16(Ah, B0, aR, 0, 0, 0);
      aZ = __builtin_amdgcn_mfma_f32_16x16x32_f16(Ah, B1, aZ, 0, 0, 0);
      aN = __builtin_amdgcn_mfma_f32_16x16x32_f16(Ah, B2, aN, 0, 0, 0);
      aR = __builtin_amdgcn_mfma_f32_16x16x32_f16(Al, B0, aR, 0, 0, 0);
      aZ = __builtin_amdgcn_mfma_f32_16x16x32_f16(Al, B1, aZ, 0, 0, 0);
      aN = __builtin_amdgcn_mfma_f32_16x16x32_f16(Al, B2, aN, 0, 0, 0);
    }
  }
}

// ------ fused layer-1 GEMM: gi = wih1@h0 (B from global) + rec = whh1@h1 -----
__device__ __forceinline__ void gemm_fused(const f16* __restrict__ A0h,
                                           const f16* __restrict__ A0l,
                                           const f16* __restrict__ A1h,
                                           const f16* __restrict__ A1l,
                                           const f16* Wsh, const f16* __restrict__ Wg,
                                           int lane, int wv, int rot,
                                           f32x4& gR, f32x4& gZ, f32x4& gN,
                                           f32x4& aR, f32x4& aZ, f32x4& aN) {
  const int q = lane >> 4, r = lane & 15;
  const f16* p0h = A0h + (size_t)(wv * 16 + r) * H_ + q * 8;
  const f16* p0l = A0l + (size_t)(wv * 16 + r) * H_ + q * 8;
  const f16* p1h = A1h + (size_t)(wv * 16 + r) * H_ + q * 8;
  const f16* p1l = A1l + (size_t)(wv * 16 + r) * H_ + q * 8;
  const f16* w0 = Wsh + ((0 * 16 + r) << 10);
  const f16* w1 = Wsh + ((1 * 16 + r) << 10);
  const f16* w2 = Wsh + ((2 * 16 + r) << 10);
  const f16* g0 = Wg + ((0 * 16 + r) << 10);
  const f16* g1 = Wg + ((1 * 16 + r) << 10);
  const f16* g2 = Wg + ((2 * 16 + r) << 10);
  const int sw = r & 7;
#pragma unroll 4
  for (int kt = 0; kt < 32; ++kt) {
    int kk = (kt + rot) & 31;
    f16x8 A0H = *(const f16x8*)(p0h + kk * 32);
    f16x8 A0L = *(const f16x8*)(p0l + kk * 32);
    f16x8 A1H = *(const f16x8*)(p1h + kk * 32);
    f16x8 A1L = *(const f16x8*)(p1l + kk * 32);
    int ko  = ((kk * 4 + q) ^ sw) << 3;   // LDS (bank-swizzled)
    int ko2 = (kk * 4 + q) << 3;          // global (linear)
    f16x8 BG0 = *(const f16x8*)(g0 + ko2);
    f16x8 BG1 = *(const f16x8*)(g1 + ko2);
    f16x8 BG2 = *(const f16x8*)(g2 + ko2);
    f16x8 BL0 = *(const f16x8*)(w0 + ko);
    f16x8 BL1 = *(const f16x8*)(w1 + ko);
    f16x8 BL2 = *(const f16x8*)(w2 + ko);
    gR = __builtin_amdgcn_mfma_f32_16x16x32_f16(A0H, BG0, gR, 0, 0, 0);
    gZ = __builtin_amdgcn_mfma_f32_16x16x32_f16(A0H, BG1, gZ, 0, 0, 0);
    gN = __builtin_amdgcn_mfma_f32_16x16x32_f16(A0H, BG2, gN, 0, 0, 0);
    gR = __builtin_amdgcn_mfma_f32_16x16x32_f16(A0L, BG0, gR, 0, 0, 0);
    gZ = __builtin_amdgcn_mfma_f32_16x16x32_f16(A0L, BG1, gZ, 0, 0, 0);
    gN = __builtin_amdgcn_mfma_f32_16x16x32_f16(A0L, BG2, gN, 0, 0, 0);
    aR = __builtin_amdgcn_mfma_f32_16x16x32_f16(A1H, BL0, aR, 0, 0, 0);
    aZ = __builtin_amdgcn_mfma_f32_16x16x32_f16(A1H, BL1, aZ, 0, 0, 0);
    aN = __builtin_amdgcn_mfma_f32_16x16x32_f16(A1H, BL2, aN, 0, 0, 0);
    aR = __builtin_amdgcn_mfma_f32_16x16x32_f16(A1L, BL0, aR, 0, 0, 0);
    aZ = __builtin_amdgcn_mfma_f32_16x16x32_f16(A1L, BL1, aZ, 0, 0, 0);
    aN = __builtin_amdgcn_mfma_f32_16x16x32_f16(A1L, BL2, aN, 0, 0, 0);
  }
}

// ---------------- x-side K=32 (padded 24) MFMA -------------------------------
__device__ __forceinline__ void gemmX(const f16* xs, const f16* wih_s, int lane, int wv,
                                      f32x4& aR, f32x4& aZ, f32x4& aNx) {
  const int q = lane >> 4, r = lane & 15;
  f16x8 Ax = *(const f16x8*)(xs + (wv * 16 + r) * 32 + q * 8);
  f16x8 B0 = *(const f16x8*)(wih_s + (0 * 16 + r) * 32 + q * 8);
  f16x8 B1 = *(const f16x8*)(wih_s + (1 * 16 + r) * 32 + q * 8);
  f16x8 B2 = *(const f16x8*)(wih_s + (2 * 16 + r) * 32 + q * 8);
  aR = __builtin_amdgcn_mfma_f32_16x16x32_f16(Ax, B0, aR, 0, 0, 0);
  aZ = __builtin_amdgcn_mfma_f32_16x16x32_f16(Ax, B1, aZ, 0, 0, 0);
  aNx = __builtin_amdgcn_mfma_f32_16x16x32_f16(Ax, B2, aNx, 0, 0, 0);
}

// ---------------- fused GRU nonlinearity + h store (hi/lo fp16) --------------
__device__ __forceinline__ void gru_epilogue(const f32x4& aR, const f32x4& aZ,
                                             const f32x4& aNh, const f32x4& aNx,
                                             float bR, float bZ, float bIN, float bHN,
                                             const f16* hph, const f16* hpl,
                                             f16* hoh, f16* hol, int u, int b0) {
#pragma unroll
  for (int i = 0; i < 4; ++i) {
    float rg = sigm(aR[i] + bR);
    float zg = sigm(aZ[i] + bZ);
    float ng = tanhf(aNx[i] + bIN + rg * (aNh[i] + bHN));
    size_t off = (size_t)(b0 + i) * H_ + u;
    float hp = (float)hph[off] + (float)hpl[off];
    float hn = (1.f - zg) * ng + zg * hp;
    f16 hh = (f16)hn;
    hoh[off] = hh;
    hol[off] = (f16)(hn - (float)hh);
  }
}

// ---------------- FC head: p = h @ fcW.T + fcb (16 blocks x 8 rows) ----------
__device__ __forceinline__ void fc_step(const f16* hh, const f16* hl,
                                        const float* fcW_s, float fcbv, int fcblk,
                                        int tid, float* out_slice, float* pdst) {
  int b_loc = tid >> 6;            // 0..7
  int l = (tid >> 3) & 7;
  int strip = tid & 7;             // lanes 0..7 within wave
  int b = fcblk * 8 + b_loc;
  const f16* ph = hh + (size_t)b * H_ + strip * 128;
  const f16* pl = hl + (size_t)b * H_ + strip * 128;
  const float* pw = fcW_s + l * H_ + strip * 128;
  float s = 0.f;
  for (int j = 0; j < 128; j += 8) {
    f16x8 a = *(const f16x8*)(ph + j);
    f16x8 c = *(const f16x8*)(pl + j);
#pragma unroll
    for (int e = 0; e < 8; ++e) s += ((float)a[e] + (float)c[e]) * pw[j + e];
  }
  s += __shfl_xor(s, 1);
  s += __shfl_xor(s, 2);
  s += __shfl_xor(s, 4);
  if (strip == 0) {
    float v = s + fcbv;
    out_slice[b * 8 + l] = v;
    pdst[b * 8 + l] = v;
  }
}

// ------------------------------- persistent kernel ---------------------------
// roles: bid 0..63  = role-0  (layer-0 GRU; decoder GRU after swap)
//        bid 64..127= role-12 (fused layer-1: gi in regs)
//        bid 128..143 = FC head
__global__ __launch_bounds__(NT, 2) void gru_persist(
    const float* __restrict__ feats, const float* __restrict__ labels,
    const float* __restrict__ wih0, const float* __restrict__ whh0,
    const float* __restrict__ bih0, const float* __restrict__ bhh0,
    const float* __restrict__ wih1, const float* __restrict__ whh1,
    const float* __restrict__ bih1, const float* __restrict__ bhh1,
    const float* __restrict__ dwih, const float* __restrict__ dwhh,
    const float* __restrict__ dbih, const float* __restrict__ dbhh,
    const float* __restrict__ fcW, const float* __restrict__ fcb,
    float* __restrict__ out, char* ws) {
  int* flags = (int*)ws;                          // init-barrier flags
  int* flags2 = (int*)(ws + 2048);                // fast-barrier flags
  int* ctrl = (int*)(ws + 4096);                  // [0]=rel [1]=done [2..9]=xcd_rank [10]=nleaders
  f16* h0r = (f16*)(ws + 8192);                   // 8 slots x [plane][128][1024]
  f16* h1r = (f16*)(ws + 8192 + 4194304);         // 8 slots (also decoder h)
  f16* wih1f = (f16*)(ws + 8192 + 8388608);       // 64 chunks x 48x1024 f16 (6 MB)
  float* pbr = (float*)(ws + 8192 + 8388608 + 12582912);  // 8 slots x 1024 f32

  const int bid = blockIdx.x, tid = threadIdx.x;
  const int lane = tid & 63, wv = tid >> 6;
  const int q = lane >> 4, r = lane & 15;
  const int role = bid >> 6;                      // 0:L0 1:L1-fused 2:FC
  const int Ubase = (bid & 63) << 4;
  const int u = Ubase + r;
  const int b0 = wv * 16 + q * 4;
  const int rot = ((bid >> 3) & 7) << 2;          // kt rotation per co-XCD block

  __shared__ __align__(16) unsigned char smem[109568];
  __shared__ int s_lead, s_nl;
  f16* Wsh = (f16*)smem;                          // 48 x 1024 fp16 (96 KB)
  f16* xs = (f16*)(smem + 98304);                 // 128 x 32 fp16
  f16* wih_s = (f16*)(smem + 106496);             // 48 x 32 fp16
  float* fcW_s = (float*)smem;                    // role 2 (FC): 8 x 1024 f32

  // zero control vars
  if (bid == 0 && tid >= 1 && tid <= 10) ctrl[tid] = 0;

  // zero initial h slots (slot 7 of both rings)
  {
    uint32_t* z0 = (uint32_t*)(h0r + 7 * HSLOT);
    uint32_t* z1 = (uint32_t*)(h1r + 7 * HSLOT);
    for (int i = bid * NT + tid; i < 131072; i += NB * NT) { z0[i] = 0; z1[i] = 0; }
  }
  for (int i = tid; i < 2048; i += NT) ((uint32_t*)xs)[i] = 0;

  // stage persistent weights
  f16* wchunk = wih1f + (size_t)(bid & 63) * 49152;   // role-12's private chunk
  if (role == 0) { stage_W48(whh0, Ubase, Wsh, tid); stage_wih(wih0, Ubase, wih_s, tid); }
  else if (role == 1) { stage_W48(whh1, Ubase, Wsh, tid); stage_W48_global(wih1, Ubase, wchunk, tid); }
  else for (int i = tid; i < 8192; i += NT) fcW_s[i] = fcW[i];

  float bR = 0.f, bZ = 0.f, bIN = 0.f, bHN = 0.f;
  if (role == 0) {
    bR = bih0[u] + bhh0[u]; bZ = bih0[1024 + u] + bhh0[1024 + u];
    bIN = bih0[2048 + u];   bHN = bhh0[2048 + u];
  } else if (role == 1) {
    bR = bih1[u] + bhh1[u]; bZ = bih1[1024 + u] + bhh1[1024 + u];
    bIN = bih1[2048 + u];   bHN = bhh1[2048 + u];
  }
  float fcbv = (role == 2) ? fcb[(tid >> 3) & 7] : 0.f;

  gbar(flags, &ctrl[0], 1);   // ctrl + zeroed slots + wih1f visible

  // leader election by PHYSICAL XCD
  if (tid == 0) {
    int xcd;
    asm volatile("s_getreg_b32 %0, hwreg(HW_REG_XCC_ID)" : "=s"(xcd));
    int old = __hip_atomic_fetch_add(&ctrl[2 + (xcd & 7)], 1, __ATOMIC_RELAXED,
                                     __HIP_MEMORY_SCOPE_AGENT);
    int ld = (old == 0) ? 1 : 0;
    if (ld) __hip_atomic_fetch_add(&ctrl[10], 1, __ATOMIC_RELAXED, __HIP_MEMORY_SCOPE_AGENT);
    s_lead = ld;
  }
  gbar(flags, &ctrl[0], 2);   // elections visible
  if (tid == 0) s_nl = __hip_atomic_load(&ctrl[10], __ATOMIC_RELAXED, __HIP_MEMORY_SCOPE_AGENT);
  __syncthreads();
  const bool lead = (s_lead != 0);
  const int NL = s_nl;
  int fp = 0;

  // =================== encoder: 513 pipelined super-ticks ====================
  // tick s: role-0 computes h0[s] (s<512); role-12 computes h1[s-1] (s>=1)
  //         from h0[s-1] (published last tick) and h1[s-2].
  for (int s = 0; s < 513; ++s) {
    if (role == 0 && s < 512) {
      // hoist x loads into regs: in flight during the whole h-gemm
      const int row = tid >> 2, k8 = tid & 3;
      float4 xa = {0, 0, 0, 0}, xb = {0, 0, 0, 0};
      if (k8 < 2) {
        const float* fpt = feats + ((size_t)row * 535 + s) * 16 + k8 * 8;
        xa = *(const float4*)fpt; xb = *(const float4*)(fpt + 4);
      } else if (k8 == 2) {
        const float* lp = labels + ((size_t)row * 512 + s) * 8;
        xa = *(const float4*)lp; xb = *(const float4*)(lp + 4);
      }
      const f16* hph = h0r + (size_t)((s + 7) & 7) * HSLOT;  // h0[s-1]
      const f16* hpl = hph + 131072;
      f16* hoh = h0r + (size_t)(s & 7) * HSLOT;              // h0[s]
      f16* hol = hoh + 131072;
      f32x4 aR = {0,0,0,0}, aZ = {0,0,0,0}, aN = {0,0,0,0}, aNx = {0,0,0,0};
      gemmK1024(hph, hpl, Wsh, lane, wv, rot, aR, aZ, aN);
      if (k8 < 3) {
        f16x8 v;
        v[0] = (f16)xa.x; v[1] = (f16)xa.y; v[2] = (f16)xa.z; v[3] = (f16)xa.w;
        v[4] = (f16)xb.x; v[5] = (f16)xb.y; v[6] = (f16)xb.z; v[7] = (f16)xb.w;
        *(f16x8*)(xs + row * 32 + ((k8 == 2) ? 16 : k8 * 8)) = v;
      }
      __syncthreads();
      gemmX(xs, wih_s, lane, wv, aR, aZ, aNx);
      gru_epilogue(aR, aZ, aN, aNx, bR, bZ, bIN, bHN, hph, hpl, hoh, hol, u, b0);
    } else if (role == 1 && s >= 1) {
      const f16* h0h = h0r + (size_t)((s + 7) & 7) * HSLOT;  // h0[s-1]
      const f16* h0l = h0h + 131072;
      const f16* h1h = h1r + (size_t)((s + 6) & 7) * HSLOT;  // h1[s-2]
      const f16* h1l = h1h + 131072;
      f16* hoh = h1r + (size_t)((s + 7) & 7) * HSLOT;        // h1[s-1]
      f16* hol = hoh + 131072;
      f32x4 gR = {0,0,0,0}, gZ = {0,0,0,0}, gN = {0,0,0,0};
      f32x4 aR = {0,0,0,0}, aZ = {0,0,0,0}, aN = {0,0,0,0};
      gemm_fused(h0h, h0l, h1h, h1l, Wsh, wchunk, lane, wv, rot,
                 gR, gZ, gN, aR, aZ, aN);
      f32x4 tR = aR + gR, tZ = aZ + gZ;
      gru_epilogue(tR, tZ, aN, gN, bR, bZ, bIN, bHN, h1h, h1l, hoh, hol, u, b0);
    }
    fastbar(flags2, &ctrl[1], ++fp, NL, lead);
  }

  // =================== decoder prologue: ps + weight swap ====================
  if (role == 2) {
    const f16* hf = h1r + 7 * HSLOT;   // h1[511] lives in slot 7
    fc_step(hf, hf + 131072, fcW_s, fcbv, bid - 128, tid, out, pbr);
  }
  if (role == 0) {
    stage_W48(dwhh, Ubase, Wsh, tid);
    stage_wih(dwih, Ubase, wih_s, tid);
    bR = dbih[u] + dbhh[u]; bZ = dbih[1024 + u] + dbhh[1024 + u];
    bIN = dbih[2048 + u];   bHN = dbhh[2048 + u];
  }
  fastbar(flags2, &ctrl[1], ++fp, NL, lead);

  // =================== decoder: 23 free-running ticks ========================
  for (int d = 0; d < 23; ++d) {
    if (role == 0) {
      const int row = tid >> 2, k8 = tid & 3;
      float4 xa = {0, 0, 0, 0}, xb = {0, 0, 0, 0};
      if (k8 < 2) {
        const float* fpt = feats + ((size_t)row * 535 + 512 + d) * 16 + k8 * 8;
        xa = *(const float4*)fpt; xb = *(const float4*)(fpt + 4);
      } else if (k8 == 2) {
        const float* pp = pbr + (size_t)(d & 7) * 1024 + row * 8;
        xa = *(const float4*)pp; xb = *(const float4*)(pp + 4);
      }
      const f16* hph = h1r + (size_t)((d + 7) & 7) * HSLOT;  // h prev (d=0 -> slot 7)
      const f16* hpl = hph + 131072;
      f16* hoh = h1r + (size_t)(d & 7) * HSLOT;              // h new
      f16* hol = hoh + 131072;
      f32x4 aR = {0,0,0,0}, aZ = {0,0,0,0}, aN = {0,0,0,0}, aNx = {0,0,0,0};
      gemmK1024(hph, hpl, Wsh, lane, wv, rot, aR, aZ, aN);
      if (k8 < 3) {
        f16x8 v;
        v[0] = (f16)xa.x; v[1] = (f16)xa.y; v[2] = (f16)xa.z; v[3] = (f16)xa.w;
        v[4] = (f16)xb.x; v[5] = (f16)xb.y; v[6] = (f16)xb.z; v[7] = (f16)xb.w;
        *(f16x8*)(xs + row * 32 + ((k8 == 2) ? 16 : k8 * 8)) = v;
      }
      __syncthreads();
      gemmX(xs, wih_s, lane, wv, aR, aZ, aNx);
      gru_epilogue(aR, aZ, aN, aNx, bR, bZ, bIN, bHN, hph, hpl, hoh, hol, u, b0);
    }
    fastbar(flags2, &ctrl[1], ++fp, NL, lead);
    if (role == 2) {
      const f16* hd = h1r + (size_t)(d & 7) * HSLOT;
      fc_step(hd, hd + 131072, fcW_s, fcbv, bid - 128, tid,
              out + (size_t)(d + 1) * 1024, pbr + (size_t)((d + 1) & 7) * 1024);
    }
    fastbar(flags2, &ctrl[1], ++fp, NL, lead);
  }
}

// ------------------------------------ host -----------------------------------
extern "C" void kernel_launch(void* const* d_in, const int* in_sizes, int n_in,
                              void* d_out, int out_size, void* d_ws, size_t ws_size,
                              hipStream_t stream) {
  (void)in_sizes; (void)n_in; (void)out_size; (void)ws_size;
  gru_persist<<<NB, NT, 0, stream>>>(
      (const float*)d_in[0], (const float*)d_in[1],
      (const float*)d_in[4], (const float*)d_in[5],
      (const float*)d_in[6], (const float*)d_in[7],
      (const float*)d_in[8], (const float*)d_in[9],
      (const float*)d_in[10], (const float*)d_in[11],
      (const float*)d_in[12], (const float*)d_in[13],
      (const float*)d_in[14], (const float*)d_in[15],
      (const float*)d_in[16], (const float*)d_in[17],
      (float*)d_out, (char*)d_ws);
}

// Round 5
// 11686.011 us; speedup vs baseline: 2.4316x; 2.4316x over previous
//
#include <hip/hip_runtime.h>
#include <cstdint>
#include <cstddef>

// GRU_56607668961499: B=128, T=512, PRED=24, F=16, L=8, H=1024
// R11: R7 structure verbatim (best passing, 11.26ms) + NON-TEMPORAL publish
// stores. Forensics: ~half of the 600KB/XCD/tick outward fetch is RFO --
// every h line (64B) is co-written 32B each by two blocks, every gi line is
// partially written, so write-back-allocate L2 must FETCH each line from MALL
// before writing (2.5MB/tick of footprint). These RFOs occupy the same
// ~200-outstanding-miss window as the real reads -> they pace the tick.
// __builtin_nontemporal_store = streaming/no-allocate hint, compiler-visible
// (vmcnt tracking intact -> fastbar's syncthreads still drains before the
// arrive flag; unlike R8's asm escape this preserves the memory model).
// R10 post-mortem: gi-fusion halved WRITE_SIZE but 2.5x'd dur -> gi was off
// the critical path; reverted.

typedef _Float16 f16;
typedef f16 f16x8 __attribute__((ext_vector_type(8)));
typedef float f32x4 __attribute__((ext_vector_type(4)));

#define NB 208
#define NT 512
#define H_ 1024
#define HSLOT 262144       // f16 per h ring slot ([plane][128][1024])
#define GSLOT 393216       // f32 per gi ring slot ([3072][128])

__device__ __forceinline__ float sigm(float x) { return 1.0f / (1.0f + __expf(-x)); }

// ---------------- init barrier (R4 style, per-block fences — proven) ---------
__device__ __forceinline__ void gbar(int* flags, int* rel, int phase) {
  __syncthreads();
  const int tid = threadIdx.x;
  if (blockIdx.x == 0) {
    if (tid == 0) {
      __builtin_amdgcn_fence(__ATOMIC_RELEASE, "agent");
      __hip_atomic_store(&flags[0], phase, __ATOMIC_RELAXED, __HIP_MEMORY_SCOPE_AGENT);
    }
    if (tid < NB) {
      while (__hip_atomic_load(&flags[tid], __ATOMIC_RELAXED, __HIP_MEMORY_SCOPE_AGENT) < phase)
        __builtin_amdgcn_s_sleep(1);
    }
    __syncthreads();
    if (tid == 0) {
      __hip_atomic_store(rel, phase, __ATOMIC_RELAXED, __HIP_MEMORY_SCOPE_AGENT);
      __builtin_amdgcn_fence(__ATOMIC_ACQUIRE, "agent");
    }
  } else {
    if (tid == 0) {
      __builtin_amdgcn_fence(__ATOMIC_RELEASE, "agent");
      __hip_atomic_store(&flags[blockIdx.x], phase, __ATOMIC_RELAXED, __HIP_MEMORY_SCOPE_AGENT);
      while (__hip_atomic_load(rel, __ATOMIC_RELAXED, __HIP_MEMORY_SCOPE_AGENT) < phase)
        __builtin_amdgcn_s_sleep(1);
      __builtin_amdgcn_fence(__ATOMIC_ACQUIRE, "agent");
    }
  }
  __syncthreads();
}

// ------- fast barrier: leader wbl2 each tick; inv only every 4th (R6) -------
__device__ __forceinline__ void fastbar(int* flags2, int* done, int fph, int nl,
                                        bool lead) {
  __syncthreads();   // drains each wave's vmcnt -> all stores complete
  const int tid = threadIdx.x;
  if (tid == 0)
    __hip_atomic_store(&flags2[blockIdx.x], fph, __ATOMIC_RELAXED, __HIP_MEMORY_SCOPE_AGENT);
  if (lead) {
    if (tid < NB) {
      while (__hip_atomic_load(&flags2[tid], __ATOMIC_RELAXED, __HIP_MEMORY_SCOPE_AGENT) < fph)
        __builtin_amdgcn_s_sleep(1);
    }
    __syncthreads();
    if (tid == 0) {
      // publish this XCD's dirty lines to the coherence point (wbl2)
      __builtin_amdgcn_fence(__ATOMIC_RELEASE, "agent");
      // ring-recycle inv: only every 4th phase (reuse distance >= 8 phases)
      if ((fph & 3) == 0)
        __builtin_amdgcn_fence(__ATOMIC_ACQUIRE, "agent");
      __hip_atomic_fetch_add(done, 1, __ATOMIC_RELAXED, __HIP_MEMORY_SCOPE_AGENT);
    }
  }
  if (tid == 0) {
    const int tgt = fph * nl;
    while (__hip_atomic_load(done, __ATOMIC_RELAXED, __HIP_MEMORY_SCOPE_AGENT) < tgt)
      __builtin_amdgcn_s_sleep(1);
  }
  __syncthreads();
}

// ------------- stage 48 rows x 1024 K of fp32 weights -> fp16 LDS, swizzled --
__device__ __forceinline__ void stage_W48(const float* __restrict__ W, int Ubase,
                                          f16* Wsh, int tid) {
  for (int i = tid; i < 6144; i += NT) {
    int row = i >> 7;      // 0..47  ([gate][unit])
    int k8 = i & 127;
    const float* src = W + ((size_t)((row >> 4) << 10) + Ubase + (row & 15)) * H_ + (k8 << 3);
    float4 a = *(const float4*)(src);
    float4 b = *(const float4*)(src + 4);
    f16x8 v;
    v[0] = (f16)a.x; v[1] = (f16)a.y; v[2] = (f16)a.z; v[3] = (f16)a.w;
    v[4] = (f16)b.x; v[5] = (f16)b.y; v[6] = (f16)b.z; v[7] = (f16)b.w;
    *(f16x8*)(Wsh + ((row << 10) + ((k8 ^ (row & 7)) << 3))) = v;
  }
}

__device__ __forceinline__ void stage_wih(const float* __restrict__ W, int Ubase,
                                          f16* wih_s, int tid) {
  for (int i = tid; i < 48 * 32; i += NT) {
    int row = i >> 5, k = i & 31;
    float v = (k < 24) ? W[((size_t)((row >> 4) << 10) + Ubase + (row & 15)) * 24 + k] : 0.f;
    wih_s[row * 32 + k] = (f16)v;
  }
}

// ---------------- K=1024 3-gate GEMM, A = hi+lo fp16 planes ------------------
__device__ __forceinline__ void gemmK1024(const f16* __restrict__ Ahp,
                                          const f16* __restrict__ Alp,
                                          const f16* Wsh, int lane, int wv, int rot,
                                          f32x4& aR, f32x4& aZ, f32x4& aN) {
  const int q = lane >> 4, r = lane & 15;
  const f16* pa = Ahp + (size_t)(wv * 16 + r) * H_ + q * 8;
  const f16* pl = Alp + (size_t)(wv * 16 + r) * H_ + q * 8;
  const f16* w0 = Wsh + ((0 * 16 + r) << 10);
  const f16* w1 = Wsh + ((1 * 16 + r) << 10);
  const f16* w2 = Wsh + ((2 * 16 + r) << 10);
  const int sw = r & 7;
  f16x8 bh[4][4], bl[4][4];
#pragma unroll
  for (int g = 0; g < 3; ++g) {
#pragma unroll
    for (int j = 0; j < 4; ++j) {
      int kk = (g * 4 + j + rot) & 31;
      bh[g][j] = *(const f16x8*)(pa + kk * 32);
      bl[g][j] = *(const f16x8*)(pl + kk * 32);
    }
  }
#pragma unroll
  for (int g = 0; g < 8; ++g) {
    if (g < 5) {
      int gg = g + 3;
#pragma unroll
      for (int j = 0; j < 4; ++j) {
        int kk = (gg * 4 + j + rot) & 31;
        bh[gg & 3][j] = *(const f16x8*)(pa + kk * 32);
        bl[gg & 3][j] = *(const f16x8*)(pl + kk * 32);
      }
    }
#pragma unroll
    for (int j = 0; j < 4; ++j) {
      int kk = (g * 4 + j + rot) & 31;
      int ko = ((kk * 4 + q) ^ sw) << 3;
      f16x8 B0 = *(const f16x8*)(w0 + ko);
      f16x8 B1 = *(const f16x8*)(w1 + ko);
      f16x8 B2 = *(const f16x8*)(w2 + ko);
      f16x8 Ah = bh[g & 3][j], Al = bl[g & 3][j];
      aR = __builtin_amdgcn_mfma_f32_16x16x32_f16(Ah, B0, aR, 0, 0, 0);
      aZ = __builtin_amdgcn_mfma_f32_16x16x32_f16(Ah, B1, aZ, 0, 0, 0);
      aN = __builtin_amdgcn_mfma_f32_16x16x32_f16(Ah, B2, aN, 0, 0, 0);
      aR = __builtin_amdgcn_mfma_f32_16x16x32_f16(Al, B0, aR, 0, 0, 0);
      aZ = __builtin_amdgcn_mfma_f32_16x16x32_f16(Al, B1, aZ, 0, 0, 0);
      aN = __builtin_amdgcn_mfma_f32_16x16x32_f16(Al, B2, aN, 0, 0, 0);
    }
  }
}

// ---------------- x-side K=32 (padded 24) MFMA -------------------------------
__device__ __forceinline__ void gemmX(const f16* xs, const f16* wih_s, int lane, int wv,
                                      f32x4& aR, f32x4& aZ, f32x4& aNx) {
  const int q = lane >> 4, r = lane & 15;
  f16x8 Ax = *(const f16x8*)(xs + (wv * 16 + r) * 32 + q * 8);
  f16x8 B0 = *(const f16x8*)(wih_s + (0 * 16 + r) * 32 + q * 8);
  f16x8 B1 = *(const f16x8*)(wih_s + (1 * 16 + r) * 32 + q * 8);
  f16x8 B2 = *(const f16x8*)(wih_s + (2 * 16 + r) * 32 + q * 8);
  aR = __builtin_amdgcn_mfma_f32_16x16x32_f16(Ax, B0, aR, 0, 0, 0);
  aZ = __builtin_amdgcn_mfma_f32_16x16x32_f16(Ax, B1, aZ, 0, 0, 0);
  aNx = __builtin_amdgcn_mfma_f32_16x16x32_f16(Ax, B2, aNx, 0, 0, 0);
}

// -------- fused GRU nonlinearity + NON-TEMPORAL h store (hi/lo fp16) ---------
__device__ __forceinline__ void gru_epilogue(const f32x4& aR, const f32x4& aZ,
                                             const f32x4& aNh, const f32x4& aNx,
                                             float bR, float bZ, float bIN, float bHN,
                                             const f16* hph, const f16* hpl,
                                             f16* hoh, f16* hol, int u, int b0) {
#pragma unroll
  for (int i = 0; i < 4; ++i) {
    float rg = sigm(aR[i] + bR);
    float zg = sigm(aZ[i] + bZ);
    float ng = tanhf(aNx[i] + bIN + rg * (aNh[i] + bHN));
    size_t off = (size_t)(b0 + i) * H_ + u;
    float hp = (float)hph[off] + (float)hpl[off];
    float hn = (1.f - zg) * ng + zg * hp;
    f16 hh = (f16)hn;
    __builtin_nontemporal_store(hh, &hoh[off]);                    // no-RFO publish
    __builtin_nontemporal_store((f16)(hn - (float)hh), &hol[off]); // no-RFO publish
  }
}

// ---------------- FC head: p = h @ fcW.T + fcb (16 blocks x 8 rows) ----------
__device__ __forceinline__ void fc_step(const f16* hh, const f16* hl,
                                        const float* fcW_s, float fcbv, int fcblk,
                                        int tid, float* out_slice, float* pdst) {
  int b_loc = tid >> 6;            // 0..7
  int l = (tid >> 3) & 7;
  int strip = tid & 7;             // lanes 0..7 within wave
  int b = fcblk * 8 + b_loc;
  const f16* ph = hh + (size_t)b * H_ + strip * 128;
  const f16* pl = hl + (size_t)b * H_ + strip * 128;
  const float* pw = fcW_s + l * H_ + strip * 128;
  float s = 0.f;
  for (int j = 0; j < 128; j += 8) {
    f16x8 a = *(const f16x8*)(ph + j);
    f16x8 c = *(const f16x8*)(pl + j);
#pragma unroll
    for (int e = 0; e < 8; ++e) s += ((float)a[e] + (float)c[e]) * pw[j + e];
  }
  s += __shfl_xor(s, 1);
  s += __shfl_xor(s, 2);
  s += __shfl_xor(s, 4);
  if (strip == 0) {
    float v = s + fcbv;
    out_slice[b * 8 + l] = v;                       // host-read output: plain
    __builtin_nontemporal_store(v, &pdst[b * 8 + l]); // decoder feedback: no-RFO
  }
}

// ------------------------------- persistent kernel ---------------------------
__global__ __launch_bounds__(NT, 2) void gru_persist(
    const float* __restrict__ feats, const float* __restrict__ labels,
    const float* __restrict__ wih0, const float* __restrict__ whh0,
    const float* __restrict__ bih0, const float* __restrict__ bhh0,
    const float* __restrict__ wih1, const float* __restrict__ whh1,
    const float* __restrict__ bih1, const float* __restrict__ bhh1,
    const float* __restrict__ dwih, const float* __restrict__ dwhh,
    const float* __restrict__ dbih, const float* __restrict__ dbhh,
    const float* __restrict__ fcW, const float* __restrict__ fcb,
    float* __restrict__ out, char* ws) {
  int* flags = (int*)ws;                          // init-barrier flags
  int* flags2 = (int*)(ws + 2048);                // fast-barrier flags
  int* ctrl = (int*)(ws + 4096);                  // [0]=rel [1]=done [2..9]=xcd_rank [10]=nleaders
  f16* h0r = (f16*)(ws + 8192);                   // 8 slots x [plane][128][1024]
  f16* h1r = (f16*)(ws + 8192 + 4194304);         // 8 slots (also decoder h)
  float* gir = (float*)(ws + 8192 + 8388608);     // 8 slots x [3072][128] f32
  float* pbr = (float*)(ws + 8192 + 8388608 + 12582912);  // 8 slots x 1024 f32

  const int bid = blockIdx.x, tid = threadIdx.x;
  const int lane = tid & 63, wv = tid >> 6;
  const int q = lane >> 4, r = lane & 15;
  const int role = bid >> 6;                      // 0:L0 1:L1i 2:L1h 3:FC
  const int Ubase = (bid & 63) << 4;
  const int u = Ubase + r;
  const int b0 = wv * 16 + q * 4;
  const int rot = ((bid >> 3) & 7) << 2;          // kt rotation per co-XCD block

  __shared__ __align__(16) unsigned char smem[109568];
  __shared__ int s_lead, s_nl;
  f16* Wsh = (f16*)smem;                          // 48 x 1024 fp16 (96 KB)
  f16* xs = (f16*)(smem + 98304);                 // 128 x 32 fp16
  f16* wih_s = (f16*)(smem + 106496);             // 48 x 32 fp16
  float* fcW_s = (float*)smem;                    // role 3: 8 x 1024 f32

  // zero control vars
  if (bid == 0 && tid >= 1 && tid <= 10) ctrl[tid] = 0;

  // zero initial h slots (slot 7 of both rings)
  {
    uint32_t* z0 = (uint32_t*)(h0r + 7 * HSLOT);
    uint32_t* z1 = (uint32_t*)(h1r + 7 * HSLOT);
    for (int i = bid * NT + tid; i < 131072; i += NB * NT) { z0[i] = 0; z1[i] = 0; }
  }
  for (int i = tid; i < 2048; i += NT) ((uint32_t*)xs)[i] = 0;

  // stage persistent weights
  if (role == 0) { stage_W48(whh0, Ubase, Wsh, tid); stage_wih(wih0, Ubase, wih_s, tid); }
  else if (role == 1) stage_W48(wih1, Ubase, Wsh, tid);
  else if (role == 2) stage_W48(whh1, Ubase, Wsh, tid);
  else for (int i = tid; i < 8192; i += NT) fcW_s[i] = fcW[i];

  float bR = 0.f, bZ = 0.f, bIN = 0.f, bHN = 0.f;
  if (role == 0) {
    bR = bih0[u] + bhh0[u]; bZ = bih0[1024 + u] + bhh0[1024 + u];
    bIN = bih0[2048 + u];   bHN = bhh0[2048 + u];
  } else if (role == 2) {
    bR = bih1[u] + bhh1[u]; bZ = bih1[1024 + u] + bhh1[1024 + u];
    bIN = bih1[2048 + u];   bHN = bhh1[2048 + u];
  }
  float fcbv = (role == 3) ? fcb[(tid >> 3) & 7] : 0.f;

  gbar(flags, &ctrl[0], 1);   // ctrl + zeroed slots visible

  // leader election by PHYSICAL XCD
  if (tid == 0) {
    int xcd;
    asm volatile("s_getreg_b32 %0, hwreg(HW_REG_XCC_ID)" : "=s"(xcd));
    int old = __hip_atomic_fetch_add(&ctrl[2 + (xcd & 7)], 1, __ATOMIC_RELAXED,
                                     __HIP_MEMORY_SCOPE_AGENT);
    int ld = (old == 0) ? 1 : 0;
    if (ld) __hip_atomic_fetch_add(&ctrl[10], 1, __ATOMIC_RELAXED, __HIP_MEMORY_SCOPE_AGENT);
    s_lead = ld;
  }
  gbar(flags, &ctrl[0], 2);   // elections visible
  if (tid == 0) s_nl = __hip_atomic_load(&ctrl[10], __ATOMIC_RELAXED, __HIP_MEMORY_SCOPE_AGENT);
  __syncthreads();
  const bool lead = (s_lead != 0);
  const int NL = s_nl;
  int fp = 0;

  // =================== encoder: 514 pipelined super-ticks ====================
  for (int s = 0; s < 514; ++s) {
    if (role == 0 && s < 512) {
      // hoist x loads into regs: in flight during the whole h-gemm
      const int row = tid >> 2, k8 = tid & 3;
      float4 xa = {0, 0, 0, 0}, xb = {0, 0, 0, 0};
      if (k8 < 2) {
        const float* fpt = feats + ((size_t)row * 535 + s) * 16 + k8 * 8;
        xa = *(const float4*)fpt; xb = *(const float4*)(fpt + 4);
      } else if (k8 == 2) {
        const float* lp = labels + ((size_t)row * 512 + s) * 8;
        xa = *(const float4*)lp; xb = *(const float4*)(lp + 4);
      }
      const f16* hph = h0r + (size_t)((s + 7) & 7) * HSLOT;  // h0[s-1]
      const f16* hpl = hph + 131072;
      f16* hoh = h0r + (size_t)(s & 7) * HSLOT;              // h0[s]
      f16* hol = hoh + 131072;
      f32x4 aR = {0,0,0,0}, aZ = {0,0,0,0}, aN = {0,0,0,0}, aNx = {0,0,0,0};
      gemmK1024(hph, hpl, Wsh, lane, wv, rot, aR, aZ, aN);
      if (k8 < 3) {
        f16x8 v;
        v[0] = (f16)xa.x; v[1] = (f16)xa.y; v[2] = (f16)xa.z; v[3] = (f16)xa.w;
        v[4] = (f16)xb.x; v[5] = (f16)xb.y; v[6] = (f16)xb.z; v[7] = (f16)xb.w;
        *(f16x8*)(xs + row * 32 + ((k8 == 2) ? 16 : k8 * 8)) = v;
      }
      __syncthreads();
      gemmX(xs, wih_s, lane, wv, aR, aZ, aNx);
      gru_epilogue(aR, aZ, aN, aNx, bR, bZ, bIN, bHN, hph, hpl, hoh, hol, u, b0);
    } else if (role == 1 && s >= 1 && s <= 512) {
      const f16* hph = h0r + (size_t)((s + 7) & 7) * HSLOT;  // h0[s-1]
      const f16* hpl = hph + 131072;
      f32x4 aR = {0,0,0,0}, aZ = {0,0,0,0}, aN = {0,0,0,0};
      gemmK1024(hph, hpl, Wsh, lane, wv, rot, aR, aZ, aN);
      float* dst = gir + (size_t)((s + 7) & 7) * GSLOT;      // gi for h0[s-1]
      __builtin_nontemporal_store(aR, (f32x4*)(dst + (size_t)u * 128 + b0));
      __builtin_nontemporal_store(aZ, (f32x4*)(dst + (size_t)(1024 + u) * 128 + b0));
      __builtin_nontemporal_store(aN, (f32x4*)(dst + (size_t)(2048 + u) * 128 + b0));
    } else if (role == 2 && s >= 2) {
      const f16* hph = h1r + (size_t)((s + 5) & 7) * HSLOT;  // h1[s-3]
      const f16* hpl = hph + 131072;
      f16* hoh = h1r + (size_t)((s + 6) & 7) * HSLOT;        // h1[s-2]
      f16* hol = hoh + 131072;
      // hoist gi loads (own-XCD L2) ahead of the h-gemm
      const float* gp = gir + (size_t)((s + 6) & 7) * GSLOT; // gi for h0[s-2]
      f32x4 gR = *(const f32x4*)(gp + (size_t)u * 128 + b0);
      f32x4 gZ = *(const f32x4*)(gp + (size_t)(1024 + u) * 128 + b0);
      f32x4 gN = *(const f32x4*)(gp + (size_t)(2048 + u) * 128 + b0);
      f32x4 aR = {0,0,0,0}, aZ = {0,0,0,0}, aN = {0,0,0,0};
      gemmK1024(hph, hpl, Wsh, lane, wv, rot, aR, aZ, aN);
      f32x4 tR = aR + gR, tZ = aZ + gZ;
      gru_epilogue(tR, tZ, aN, gN, bR, bZ, bIN, bHN, hph, hpl, hoh, hol, u, b0);
    }
    fastbar(flags2, &ctrl[1], ++fp, NL, lead);
  }

  // =================== decoder prologue: ps + weight swap ====================
  if (role == 3) {
    const f16* hf = h1r + 7 * HSLOT;   // h1[511] lives in slot 7
    fc_step(hf, hf + 131072, fcW_s, fcbv, bid - 192, tid, out, pbr);
  }
  if (role == 0) {
    stage_W48(dwhh, Ubase, Wsh, tid);
    stage_wih(dwih, Ubase, wih_s, tid);
    bR = dbih[u] + dbhh[u]; bZ = dbih[1024 + u] + dbhh[1024 + u];
    bIN = dbih[2048 + u];   bHN = dbhh[2048 + u];
  }
  fastbar(flags2, &ctrl[1], ++fp, NL, lead);

  // =================== decoder: 23 free-running ticks ========================
  for (int d = 0; d < 23; ++d) {
    if (role == 0) {
      const int row = tid >> 2, k8 = tid & 3;
      float4 xa = {0, 0, 0, 0}, xb = {0, 0, 0, 0};
      if (k8 < 2) {
        const float* fpt = feats + ((size_t)row * 535 + 512 + d) * 16 + k8 * 8;
        xa = *(const float4*)fpt; xb = *(const float4*)(fpt + 4);
      } else if (k8 == 2) {
        const float* pp = pbr + (size_t)(d & 7) * 1024 + row * 8;
        xa = *(const float4*)pp; xb = *(const float4*)(pp + 4);
      }
      const f16* hph = h1r + (size_t)((d + 7) & 7) * HSLOT;  // h prev (d=0 -> slot 7)
      const f16* hpl = hph + 131072;
      f16* hoh = h1r + (size_t)(d & 7) * HSLOT;              // h new
      f16* hol = hoh + 131072;
      f32x4 aR = {0,0,0,0}, aZ = {0,0,0,0}, aN = {0,0,0,0}, aNx = {0,0,0,0};
      gemmK1024(hph, hpl, Wsh, lane, wv, rot, aR, aZ, aN);
      if (k8 < 3) {
        f16x8 v;
        v[0] = (f16)xa.x; v[1] = (f16)xa.y; v[2] = (f16)xa.z; v[3] = (f16)xa.w;
        v[4] = (f16)xb.x; v[5] = (f16)xb.y; v[6] = (f16)xb.z; v[7] = (f16)xb.w;
        *(f16x8*)(xs + row * 32 + ((k8 == 2) ? 16 : k8 * 8)) = v;
      }
      __syncthreads();
      gemmX(xs, wih_s, lane, wv, aR, aZ, aNx);
      gru_epilogue(aR, aZ, aN, aNx, bR, bZ, bIN, bHN, hph, hpl, hoh, hol, u, b0);
    }
    fastbar(flags2, &ctrl[1], ++fp, NL, lead);
    if (role == 3) {
      const f16* hd = h1r + (size_t)(d & 7) * HSLOT;
      fc_step(hd, hd + 131072, fcW_s, fcbv, bid - 192, tid,
              out + (size_t)(d + 1) * 1024, pbr + (size_t)((d + 1) & 7) * 1024);
    }
    fastbar(flags2, &ctrl[1], ++fp, NL, lead);
  }
}

// ------------------------------------ host -----------------------------------
extern "C" void kernel_launch(void* const* d_in, const int* in_sizes, int n_in,
                              void* d_out, int out_size, void* d_ws, size_t ws_size,
                              hipStream_t stream) {
  (void)in_sizes; (void)n_in; (void)out_size; (void)ws_size;
  gru_persist<<<NB, NT, 0, stream>>>(
      (const float*)d_in[0], (const float*)d_in[1],
      (const float*)d_in[4], (const float*)d_in[5],
      (const float*)d_in[6], (const float*)d_in[7],
      (const float*)d_in[8], (const float*)d_in[9],
      (const float*)d_in[10], (const float*)d_in[11],
      (const float*)d_in[12], (const float*)d_in[13],
      (const float*)d_in[14], (const float*)d_in[15],
      (const float*)d_in[16], (const float*)d_in[17],
      (float*)d_out, (char*)d_ws);
}

// Round 6
// 7181.207 us; speedup vs baseline: 3.9570x; 1.6273x over previous
//
#include <hip/hip_runtime.h>
#include <cstdint>
#include <cstddef>

// GRU_56607668961499: B=128, T=512, PRED=24, F=16, L=8, H=1024
// R12: SINGLE-PLANE f16 h (drop the hi/lo double-f16 decomposition).
// Cross-round forensics: tick time == slowest-block fetch bytes / ~24 GB/s
// (R7: 512KB -> 21us; R10-fused: 1.1MB -> 55us) == the per-CU VMEM ceiling
// (~10 B/cy/CU) for beyond-L2 data. Nothing that left per-block bytes alone
// (rot, pipelining, inv cadence, NT stores) moved dur; R10 doubled bytes and
// doubled the tick. So: halve the h slot (512->256KB) by storing h as plain
// RTN f16. Precision: f16 weights already inject ~4.9e-4/step; lo-plane only
// suppressed a same-order term. absmax predicted ~2-5e-3 vs 8.5e-3 threshold.
// h-GEMM MFMA count and LDS-B reads also halve (96 MFMA/wave).
// Publish/barrier protocol: R6/R7 verbatim (plain stores, leader wbl2/tick,
// inv every 4th phase). R11's NT stores reverted (FETCH unchanged -> no RFO
// existed; WRITE rose; slight regression).

typedef _Float16 f16;
typedef f16 f16x8 __attribute__((ext_vector_type(8)));
typedef float f32x4 __attribute__((ext_vector_type(4)));

#define NB 208
#define NT 512
#define H_ 1024
#define HSLOT 131072       // f16 per h ring slot ([128][1024])
#define GSLOT 393216       // f32 per gi ring slot ([3072][128])

__device__ __forceinline__ float sigm(float x) { return 1.0f / (1.0f + __expf(-x)); }

// ---------------- init barrier (R4 style, per-block fences — proven) ---------
__device__ __forceinline__ void gbar(int* flags, int* rel, int phase) {
  __syncthreads();
  const int tid = threadIdx.x;
  if (blockIdx.x == 0) {
    if (tid == 0) {
      __builtin_amdgcn_fence(__ATOMIC_RELEASE, "agent");
      __hip_atomic_store(&flags[0], phase, __ATOMIC_RELAXED, __HIP_MEMORY_SCOPE_AGENT);
    }
    if (tid < NB) {
      while (__hip_atomic_load(&flags[tid], __ATOMIC_RELAXED, __HIP_MEMORY_SCOPE_AGENT) < phase)
        __builtin_amdgcn_s_sleep(1);
    }
    __syncthreads();
    if (tid == 0) {
      __hip_atomic_store(rel, phase, __ATOMIC_RELAXED, __HIP_MEMORY_SCOPE_AGENT);
      __builtin_amdgcn_fence(__ATOMIC_ACQUIRE, "agent");
    }
  } else {
    if (tid == 0) {
      __builtin_amdgcn_fence(__ATOMIC_RELEASE, "agent");
      __hip_atomic_store(&flags[blockIdx.x], phase, __ATOMIC_RELAXED, __HIP_MEMORY_SCOPE_AGENT);
      while (__hip_atomic_load(rel, __ATOMIC_RELAXED, __HIP_MEMORY_SCOPE_AGENT) < phase)
        __builtin_amdgcn_s_sleep(1);
      __builtin_amdgcn_fence(__ATOMIC_ACQUIRE, "agent");
    }
  }
  __syncthreads();
}

// ------- fast barrier: leader wbl2 each tick; inv only every 4th (R6) -------
__device__ __forceinline__ void fastbar(int* flags2, int* done, int fph, int nl,
                                        bool lead) {
  __syncthreads();   // drains each wave's vmcnt -> all stores complete in L2
  const int tid = threadIdx.x;
  if (tid == 0)
    __hip_atomic_store(&flags2[blockIdx.x], fph, __ATOMIC_RELAXED, __HIP_MEMORY_SCOPE_AGENT);
  if (lead) {
    if (tid < NB) {
      while (__hip_atomic_load(&flags2[tid], __ATOMIC_RELAXED, __HIP_MEMORY_SCOPE_AGENT) < fph)
        __builtin_amdgcn_s_sleep(1);
    }
    __syncthreads();
    if (tid == 0) {
      // publish this XCD's dirty lines to the coherence point (wbl2)
      __builtin_amdgcn_fence(__ATOMIC_RELEASE, "agent");
      // ring-recycle inv: only every 4th phase (reuse distance >= 8 phases)
      if ((fph & 3) == 0)
        __builtin_amdgcn_fence(__ATOMIC_ACQUIRE, "agent");
      __hip_atomic_fetch_add(done, 1, __ATOMIC_RELAXED, __HIP_MEMORY_SCOPE_AGENT);
    }
  }
  if (tid == 0) {
    const int tgt = fph * nl;
    while (__hip_atomic_load(done, __ATOMIC_RELAXED, __HIP_MEMORY_SCOPE_AGENT) < tgt)
      __builtin_amdgcn_s_sleep(1);
  }
  __syncthreads();
}

// ------------- stage 48 rows x 1024 K of fp32 weights -> fp16 LDS, swizzled --
__device__ __forceinline__ void stage_W48(const float* __restrict__ W, int Ubase,
                                          f16* Wsh, int tid) {
  for (int i = tid; i < 6144; i += NT) {
    int row = i >> 7;      // 0..47  ([gate][unit])
    int k8 = i & 127;
    const float* src = W + ((size_t)((row >> 4) << 10) + Ubase + (row & 15)) * H_ + (k8 << 3);
    float4 a = *(const float4*)(src);
    float4 b = *(const float4*)(src + 4);
    f16x8 v;
    v[0] = (f16)a.x; v[1] = (f16)a.y; v[2] = (f16)a.z; v[3] = (f16)a.w;
    v[4] = (f16)b.x; v[5] = (f16)b.y; v[6] = (f16)b.z; v[7] = (f16)b.w;
    *(f16x8*)(Wsh + ((row << 10) + ((k8 ^ (row & 7)) << 3))) = v;
  }
}

__device__ __forceinline__ void stage_wih(const float* __restrict__ W, int Ubase,
                                          f16* wih_s, int tid) {
  for (int i = tid; i < 48 * 32; i += NT) {
    int row = i >> 5, k = i & 31;
    float v = (k < 24) ? W[((size_t)((row >> 4) << 10) + Ubase + (row & 15)) * 24 + k] : 0.f;
    wih_s[row * 32 + k] = (f16)v;
  }
}

// ---------------- K=1024 3-gate GEMM, A = single f16 plane -------------------
__device__ __forceinline__ void gemmK1024(const f16* __restrict__ Ahp,
                                          const f16* Wsh, int lane, int wv, int rot,
                                          f32x4& aR, f32x4& aZ, f32x4& aN) {
  const int q = lane >> 4, r = lane & 15;
  const f16* pa = Ahp + (size_t)(wv * 16 + r) * H_ + q * 8;
  const f16* w0 = Wsh + ((0 * 16 + r) << 10);
  const f16* w1 = Wsh + ((1 * 16 + r) << 10);
  const f16* w2 = Wsh + ((2 * 16 + r) << 10);
  const int sw = r & 7;
  f16x8 bh[4][4];
#pragma unroll
  for (int g = 0; g < 3; ++g) {
#pragma unroll
    for (int j = 0; j < 4; ++j) {
      int kk = (g * 4 + j + rot) & 31;
      bh[g][j] = *(const f16x8*)(pa + kk * 32);
    }
  }
#pragma unroll
  for (int g = 0; g < 8; ++g) {
    if (g < 5) {
      int gg = g + 3;
#pragma unroll
      for (int j = 0; j < 4; ++j) {
        int kk = (gg * 4 + j + rot) & 31;
        bh[gg & 3][j] = *(const f16x8*)(pa + kk * 32);
      }
    }
#pragma unroll
    for (int j = 0; j < 4; ++j) {
      int kk = (g * 4 + j + rot) & 31;
      int ko = ((kk * 4 + q) ^ sw) << 3;
      f16x8 B0 = *(const f16x8*)(w0 + ko);
      f16x8 B1 = *(const f16x8*)(w1 + ko);
      f16x8 B2 = *(const f16x8*)(w2 + ko);
      f16x8 Ah = bh[g & 3][j];
      aR = __builtin_amdgcn_mfma_f32_16x16x32_f16(Ah, B0, aR, 0, 0, 0);
      aZ = __builtin_amdgcn_mfma_f32_16x16x32_f16(Ah, B1, aZ, 0, 0, 0);
      aN = __builtin_amdgcn_mfma_f32_16x16x32_f16(Ah, B2, aN, 0, 0, 0);
    }
  }
}

// ---------------- x-side K=32 (padded 24) MFMA -------------------------------
__device__ __forceinline__ void gemmX(const f16* xs, const f16* wih_s, int lane, int wv,
                                      f32x4& aR, f32x4& aZ, f32x4& aNx) {
  const int q = lane >> 4, r = lane & 15;
  f16x8 Ax = *(const f16x8*)(xs + (wv * 16 + r) * 32 + q * 8);
  f16x8 B0 = *(const f16x8*)(wih_s + (0 * 16 + r) * 32 + q * 8);
  f16x8 B1 = *(const f16x8*)(wih_s + (1 * 16 + r) * 32 + q * 8);
  f16x8 B2 = *(const f16x8*)(wih_s + (2 * 16 + r) * 32 + q * 8);
  aR = __builtin_amdgcn_mfma_f32_16x16x32_f16(Ax, B0, aR, 0, 0, 0);
  aZ = __builtin_amdgcn_mfma_f32_16x16x32_f16(Ax, B1, aZ, 0, 0, 0);
  aNx = __builtin_amdgcn_mfma_f32_16x16x32_f16(Ax, B2, aNx, 0, 0, 0);
}

// ---------------- fused GRU nonlinearity + h store (single f16) --------------
__device__ __forceinline__ void gru_epilogue(const f32x4& aR, const f32x4& aZ,
                                             const f32x4& aNh, const f32x4& aNx,
                                             float bR, float bZ, float bIN, float bHN,
                                             const f16* hph, f16* hoh, int u, int b0) {
#pragma unroll
  for (int i = 0; i < 4; ++i) {
    float rg = sigm(aR[i] + bR);
    float zg = sigm(aZ[i] + bZ);
    float ng = tanhf(aNx[i] + bIN + rg * (aNh[i] + bHN));
    size_t off = (size_t)(b0 + i) * H_ + u;
    float hp = (float)hph[off];
    float hn = (1.f - zg) * ng + zg * hp;
    hoh[off] = (f16)hn;
  }
}

// ---------------- FC head: p = h @ fcW.T + fcb (16 blocks x 8 rows) ----------
__device__ __forceinline__ void fc_step(const f16* hh, const float* fcW_s,
                                        float fcbv, int fcblk,
                                        int tid, float* out_slice, float* pdst) {
  int b_loc = tid >> 6;            // 0..7
  int l = (tid >> 3) & 7;
  int strip = tid & 7;             // lanes 0..7 within wave
  int b = fcblk * 8 + b_loc;
  const f16* ph = hh + (size_t)b * H_ + strip * 128;
  const float* pw = fcW_s + l * H_ + strip * 128;
  float s = 0.f;
  for (int j = 0; j < 128; j += 8) {
    f16x8 a = *(const f16x8*)(ph + j);
#pragma unroll
    for (int e = 0; e < 8; ++e) s += (float)a[e] * pw[j + e];
  }
  s += __shfl_xor(s, 1);
  s += __shfl_xor(s, 2);
  s += __shfl_xor(s, 4);
  if (strip == 0) {
    float v = s + fcbv;
    out_slice[b * 8 + l] = v;
    pdst[b * 8 + l] = v;
  }
}

// ------------------------------- persistent kernel ---------------------------
__global__ __launch_bounds__(NT, 2) void gru_persist(
    const float* __restrict__ feats, const float* __restrict__ labels,
    const float* __restrict__ wih0, const float* __restrict__ whh0,
    const float* __restrict__ bih0, const float* __restrict__ bhh0,
    const float* __restrict__ wih1, const float* __restrict__ whh1,
    const float* __restrict__ bih1, const float* __restrict__ bhh1,
    const float* __restrict__ dwih, const float* __restrict__ dwhh,
    const float* __restrict__ dbih, const float* __restrict__ dbhh,
    const float* __restrict__ fcW, const float* __restrict__ fcb,
    float* __restrict__ out, char* ws) {
  int* flags = (int*)ws;                          // init-barrier flags
  int* flags2 = (int*)(ws + 2048);                // fast-barrier flags
  int* ctrl = (int*)(ws + 4096);                  // [0]=rel [1]=done [2..9]=xcd_rank [10]=nleaders
  f16* h0r = (f16*)(ws + 8192);                   // 8 slots x [128][1024] f16 (2MB)
  f16* h1r = (f16*)(ws + 8192 + 2097152);         // 8 slots (also decoder h)
  float* gir = (float*)(ws + 8192 + 4194304);     // 8 slots x [3072][128] f32 (12MB)
  float* pbr = (float*)(ws + 8192 + 4194304 + 12582912);  // 8 slots x 1024 f32

  const int bid = blockIdx.x, tid = threadIdx.x;
  const int lane = tid & 63, wv = tid >> 6;
  const int q = lane >> 4, r = lane & 15;
  const int role = bid >> 6;                      // 0:L0 1:L1i 2:L1h 3:FC
  const int Ubase = (bid & 63) << 4;
  const int u = Ubase + r;
  const int b0 = wv * 16 + q * 4;
  const int rot = ((bid >> 3) & 7) << 2;          // kt rotation per co-XCD block

  __shared__ __align__(16) unsigned char smem[109568];
  __shared__ int s_lead, s_nl;
  f16* Wsh = (f16*)smem;                          // 48 x 1024 fp16 (96 KB)
  f16* xs = (f16*)(smem + 98304);                 // 128 x 32 fp16
  f16* wih_s = (f16*)(smem + 106496);             // 48 x 32 fp16
  float* fcW_s = (float*)smem;                    // role 3: 8 x 1024 f32

  // zero control vars
  if (bid == 0 && tid >= 1 && tid <= 10) ctrl[tid] = 0;

  // zero initial h slots (slot 7 of both rings)
  {
    uint32_t* z0 = (uint32_t*)(h0r + 7 * HSLOT);
    uint32_t* z1 = (uint32_t*)(h1r + 7 * HSLOT);
    for (int i = bid * NT + tid; i < 65536; i += NB * NT) { z0[i] = 0; z1[i] = 0; }
  }
  for (int i = tid; i < 2048; i += NT) ((uint32_t*)xs)[i] = 0;

  // stage persistent weights
  if (role == 0) { stage_W48(whh0, Ubase, Wsh, tid); stage_wih(wih0, Ubase, wih_s, tid); }
  else if (role == 1) stage_W48(wih1, Ubase, Wsh, tid);
  else if (role == 2) stage_W48(whh1, Ubase, Wsh, tid);
  else for (int i = tid; i < 8192; i += NT) fcW_s[i] = fcW[i];

  float bR = 0.f, bZ = 0.f, bIN = 0.f, bHN = 0.f;
  if (role == 0) {
    bR = bih0[u] + bhh0[u]; bZ = bih0[1024 + u] + bhh0[1024 + u];
    bIN = bih0[2048 + u];   bHN = bhh0[2048 + u];
  } else if (role == 2) {
    bR = bih1[u] + bhh1[u]; bZ = bih1[1024 + u] + bhh1[1024 + u];
    bIN = bih1[2048 + u];   bHN = bhh1[2048 + u];
  }
  float fcbv = (role == 3) ? fcb[(tid >> 3) & 7] : 0.f;

  gbar(flags, &ctrl[0], 1);   // ctrl + zeroed slots visible

  // leader election by PHYSICAL XCD
  if (tid == 0) {
    int xcd;
    asm volatile("s_getreg_b32 %0, hwreg(HW_REG_XCC_ID)" : "=s"(xcd));
    int old = __hip_atomic_fetch_add(&ctrl[2 + (xcd & 7)], 1, __ATOMIC_RELAXED,
                                     __HIP_MEMORY_SCOPE_AGENT);
    int ld = (old == 0) ? 1 : 0;
    if (ld) __hip_atomic_fetch_add(&ctrl[10], 1, __ATOMIC_RELAXED, __HIP_MEMORY_SCOPE_AGENT);
    s_lead = ld;
  }
  gbar(flags, &ctrl[0], 2);   // elections visible
  if (tid == 0) s_nl = __hip_atomic_load(&ctrl[10], __ATOMIC_RELAXED, __HIP_MEMORY_SCOPE_AGENT);
  __syncthreads();
  const bool lead = (s_lead != 0);
  const int NL = s_nl;
  int fp = 0;

  // =================== encoder: 514 pipelined super-ticks ====================
  for (int s = 0; s < 514; ++s) {
    if (role == 0 && s < 512) {
      // hoist x loads into regs: in flight during the whole h-gemm
      const int row = tid >> 2, k8 = tid & 3;
      float4 xa = {0, 0, 0, 0}, xb = {0, 0, 0, 0};
      if (k8 < 2) {
        const float* fpt = feats + ((size_t)row * 535 + s) * 16 + k8 * 8;
        xa = *(const float4*)fpt; xb = *(const float4*)(fpt + 4);
      } else if (k8 == 2) {
        const float* lp = labels + ((size_t)row * 512 + s) * 8;
        xa = *(const float4*)lp; xb = *(const float4*)(lp + 4);
      }
      const f16* hph = h0r + (size_t)((s + 7) & 7) * HSLOT;  // h0[s-1]
      f16* hoh = h0r + (size_t)(s & 7) * HSLOT;              // h0[s]
      f32x4 aR = {0,0,0,0}, aZ = {0,0,0,0}, aN = {0,0,0,0}, aNx = {0,0,0,0};
      gemmK1024(hph, Wsh, lane, wv, rot, aR, aZ, aN);
      if (k8 < 3) {
        f16x8 v;
        v[0] = (f16)xa.x; v[1] = (f16)xa.y; v[2] = (f16)xa.z; v[3] = (f16)xa.w;
        v[4] = (f16)xb.x; v[5] = (f16)xb.y; v[6] = (f16)xb.z; v[7] = (f16)xb.w;
        *(f16x8*)(xs + row * 32 + ((k8 == 2) ? 16 : k8 * 8)) = v;
      }
      __syncthreads();
      gemmX(xs, wih_s, lane, wv, aR, aZ, aNx);
      gru_epilogue(aR, aZ, aN, aNx, bR, bZ, bIN, bHN, hph, hoh, u, b0);
    } else if (role == 1 && s >= 1 && s <= 512) {
      const f16* hph = h0r + (size_t)((s + 7) & 7) * HSLOT;  // h0[s-1]
      f32x4 aR = {0,0,0,0}, aZ = {0,0,0,0}, aN = {0,0,0,0};
      gemmK1024(hph, Wsh, lane, wv, rot, aR, aZ, aN);
      float* dst = gir + (size_t)((s + 7) & 7) * GSLOT;      // gi for h0[s-1]
      *(f32x4*)(dst + (size_t)u * 128 + b0) = aR;
      *(f32x4*)(dst + (size_t)(1024 + u) * 128 + b0) = aZ;
      *(f32x4*)(dst + (size_t)(2048 + u) * 128 + b0) = aN;
    } else if (role == 2 && s >= 2) {
      const f16* hph = h1r + (size_t)((s + 5) & 7) * HSLOT;  // h1[s-3]
      f16* hoh = h1r + (size_t)((s + 6) & 7) * HSLOT;        // h1[s-2]
      // hoist gi loads (own-XCD L2) ahead of the h-gemm
      const float* gp = gir + (size_t)((s + 6) & 7) * GSLOT; // gi for h0[s-2]
      f32x4 gR = *(const f32x4*)(gp + (size_t)u * 128 + b0);
      f32x4 gZ = *(const f32x4*)(gp + (size_t)(1024 + u) * 128 + b0);
      f32x4 gN = *(const f32x4*)(gp + (size_t)(2048 + u) * 128 + b0);
      f32x4 aR = {0,0,0,0}, aZ = {0,0,0,0}, aN = {0,0,0,0};
      gemmK1024(hph, Wsh, lane, wv, rot, aR, aZ, aN);
      f32x4 tR = aR + gR, tZ = aZ + gZ;
      gru_epilogue(tR, tZ, aN, gN, bR, bZ, bIN, bHN, hph, hoh, u, b0);
    }
    fastbar(flags2, &ctrl[1], ++fp, NL, lead);
  }

  // =================== decoder prologue: ps + weight swap ====================
  if (role == 3) {
    const f16* hf = h1r + 7 * HSLOT;   // h1[511] lives in slot 7
    fc_step(hf, fcW_s, fcbv, bid - 192, tid, out, pbr);
  }
  if (role == 0) {
    stage_W48(dwhh, Ubase, Wsh, tid);
    stage_wih(dwih, Ubase, wih_s, tid);
    bR = dbih[u] + dbhh[u]; bZ = dbih[1024 + u] + dbhh[1024 + u];
    bIN = dbih[2048 + u];   bHN = dbhh[2048 + u];
  }
  fastbar(flags2, &ctrl[1], ++fp, NL, lead);

  // =================== decoder: 23 free-running ticks ========================
  for (int d = 0; d < 23; ++d) {
    if (role == 0) {
      const int row = tid >> 2, k8 = tid & 3;
      float4 xa = {0, 0, 0, 0}, xb = {0, 0, 0, 0};
      if (k8 < 2) {
        const float* fpt = feats + ((size_t)row * 535 + 512 + d) * 16 + k8 * 8;
        xa = *(const float4*)fpt; xb = *(const float4*)(fpt + 4);
      } else if (k8 == 2) {
        const float* pp = pbr + (size_t)(d & 7) * 1024 + row * 8;
        xa = *(const float4*)pp; xb = *(const float4*)(pp + 4);
      }
      const f16* hph = h1r + (size_t)((d + 7) & 7) * HSLOT;  // h prev (d=0 -> slot 7)
      f16* hoh = h1r + (size_t)(d & 7) * HSLOT;              // h new
      f32x4 aR = {0,0,0,0}, aZ = {0,0,0,0}, aN = {0,0,0,0}, aNx = {0,0,0,0};
      gemmK1024(hph, Wsh, lane, wv, rot, aR, aZ, aN);
      if (k8 < 3) {
        f16x8 v;
        v[0] = (f16)xa.x; v[1] = (f16)xa.y; v[2] = (f16)xa.z; v[3] = (f16)xa.w;
        v[4] = (f16)xb.x; v[5] = (f16)xb.y; v[6] = (f16)xb.z; v[7] = (f16)xb.w;
        *(f16x8*)(xs + row * 32 + ((k8 == 2) ? 16 : k8 * 8)) = v;
      }
      __syncthreads();
      gemmX(xs, wih_s, lane, wv, aR, aZ, aNx);
      gru_epilogue(aR, aZ, aN, aNx, bR, bZ, bIN, bHN, hph, hoh, u, b0);
    }
    fastbar(flags2, &ctrl[1], ++fp, NL, lead);
    if (role == 3) {
      const f16* hd = h1r + (size_t)(d & 7) * HSLOT;
      fc_step(hd, fcW_s, fcbv, bid - 192, tid,
              out + (size_t)(d + 1) * 1024, pbr + (size_t)((d + 1) & 7) * 1024);
    }
    fastbar(flags2, &ctrl[1], ++fp, NL, lead);
  }
}

// ------------------------------------ host -----------------------------------
extern "C" void kernel_launch(void* const* d_in, const int* in_sizes, int n_in,
                              void* d_out, int out_size, void* d_ws, size_t ws_size,
                              hipStream_t stream) {
  (void)in_sizes; (void)n_in; (void)out_size; (void)ws_size;
  gru_persist<<<NB, NT, 0, stream>>>(
      (const float*)d_in[0], (const float*)d_in[1],
      (const float*)d_in[4], (const float*)d_in[5],
      (const float*)d_in[6], (const float*)d_in[7],
      (const float*)d_in[8], (const float*)d_in[9],
      (const float*)d_in[10], (const float*)d_in[11],
      (const float*)d_in[12], (const float*)d_in[13],
      (const float*)d_in[14], (const float*)d_in[15],
      (const float*)d_in[16], (const float*)d_in[17],
      (float*)d_out, (char*)d_ws);
}